// Round 3
// baseline (50.540 us; speedup 1.0000x reference)
//
#include <hip/hip_runtime.h>
#include <stdint.h>

#define NV 4096
#define KS 17

typedef __attribute__((ext_vector_type(8))) short bf16x8;
typedef __attribute__((ext_vector_type(4))) float f32x4;

__device__ __forceinline__ unsigned short f2bf(float f) {
  union { float f; unsigned int u; } v; v.f = f;
  unsigned int r = v.u + 0x7FFF + ((v.u >> 16) & 1);  // RNE
  return (unsigned short)(r >> 16);
}

// fused prep: blocks 0..2047 convert feature_map f32->bf16 (4 elems/thread);
// blocks 2048..2319 permute weights (64 x 1088, f=c*17+k) -> Wb[k][o][c] bf16.
__global__ __launch_bounds__(256)
void prep(const float* __restrict__ fm, const float* __restrict__ w,
          unsigned short* __restrict__ fmb, unsigned short* __restrict__ wb) {
  int blk = blockIdx.x;
  if (blk < 2048) {
    int i = (blk * 256 + threadIdx.x) * 4;
    float4 v = *(const float4*)(fm + i);
    ushort4 o;
    o.x = f2bf(v.x); o.y = f2bf(v.y); o.z = f2bf(v.z); o.w = f2bf(v.w);
    *(ushort4*)(fmb + i) = o;
  } else {
    int t = (blk - 2048) * 256 + threadIdx.x;  // 0..69631 (= 17*64*64)
    int c = t & 63;
    int o = (t >> 6) & 63;
    int k = t >> 12;
    wb[t] = f2bf(w[o * 1088 + c * 17 + k]);
  }
}

// slot K -> source vertex row for this lane (K=0: self, else neighbor K-1).
// Fully compile-time component selection -> registers, never scratch.
template<int K>
__device__ __forceinline__ int svsel(int row, const int4* iv) {
  if constexpr (K == 0) {
    return row;
  } else {
    constexpr int j = (K - 1) >> 2;
    constexpr int c = (K - 1) & 3;
    int4 v = iv[j];
    if constexpr (c == 0) return v.x;
    else if constexpr (c == 1) return v.y;
    else if constexpr (c == 2) return v.z;
    else return v.w;
  }
}

// Barrier-free, LDS-free gather-GEMM.
// Block = 4 waves x 64 threads; wave owns 16 vertices x 64 out-channels.
// Block covers 64 vertices x 64 channels; 64 blocks/batch x 8 batches = 512.
// Pipeline: named X/Y register double-buffer, depth 2, macro-unrolled.
__global__ __launch_bounds__(256, 3)
void conv_main(const int* __restrict__ nbr, const unsigned short* __restrict__ fmb,
               const unsigned short* __restrict__ wb, const float* __restrict__ bias,
               float* __restrict__ out) {
  const int bid = blockIdx.x;
  const int b = bid & 7;                 // batch == XCD (bijective swizzle)
  const int vtile = (bid >> 3) * 64;

  const int tid = threadIdx.x;
  const int lane = tid & 63;
  const int lm = lane & 15;
  const int lk = lane >> 4;
  const int wv = tid >> 6;

  const int row = vtile + wv * 16 + lm;  // this lane's vertex row
  const bf16x8* fb = (const bf16x8*)(fmb + (size_t)b * NV * 64);
  const bf16x8* wq = (const bf16x8*)wb + (lm * 8 + lk);

  // 16 neighbor indices for this row
  int4 iv[4];
  {
    const int4* nr = (const int4*)(nbr + ((size_t)b * NV + row) * 16);
    iv[0] = nr[0]; iv[1] = nr[1]; iv[2] = nr[2]; iv[3] = nr[3];
  }

  f32x4 acc0 = {0.f, 0.f, 0.f, 0.f}, acc1 = {0.f, 0.f, 0.f, 0.f};
  f32x4 acc2 = {0.f, 0.f, 0.f, 0.f}, acc3 = {0.f, 0.f, 0.f, 0.f};

  // stage registers: A (2 halves of K=64) + B (4 n-tiles x 2 halves)
  bf16x8 A0X, A1X, B00X, B01X, B10X, B11X, B20X, B21X, B30X, B31X;
  bf16x8 A0Y, A1Y, B00Y, B01Y, B10Y, B11Y, B20Y, B21Y, B30Y, B31Y;

#define LOAD(S, K) {                                         \
    const int sv_ = svsel<K>(row, iv);                       \
    const bf16x8* p_ = fb + (size_t)sv_ * 8;                 \
    A0##S = p_[lk];                                          \
    A1##S = p_[4 + lk];                                      \
    const bf16x8* q_ = wq + (K) * 512;                       \
    B00##S = q_[0];   B01##S = q_[4];                        \
    B10##S = q_[128]; B11##S = q_[132];                      \
    B20##S = q_[256]; B21##S = q_[260];                      \
    B30##S = q_[384]; B31##S = q_[388];                      \
  }

#define MM(S) {                                                              \
    acc0 = __builtin_amdgcn_mfma_f32_16x16x32_bf16(A0##S, B00##S, acc0, 0, 0, 0); \
    acc1 = __builtin_amdgcn_mfma_f32_16x16x32_bf16(A0##S, B10##S, acc1, 0, 0, 0); \
    acc2 = __builtin_amdgcn_mfma_f32_16x16x32_bf16(A0##S, B20##S, acc2, 0, 0, 0); \
    acc3 = __builtin_amdgcn_mfma_f32_16x16x32_bf16(A0##S, B30##S, acc3, 0, 0, 0); \
    acc0 = __builtin_amdgcn_mfma_f32_16x16x32_bf16(A1##S, B01##S, acc0, 0, 0, 0); \
    acc1 = __builtin_amdgcn_mfma_f32_16x16x32_bf16(A1##S, B11##S, acc1, 0, 0, 0); \
    acc2 = __builtin_amdgcn_mfma_f32_16x16x32_bf16(A1##S, B21##S, acc2, 0, 0, 0); \
    acc3 = __builtin_amdgcn_mfma_f32_16x16x32_bf16(A1##S, B31##S, acc3, 0, 0, 0); \
  }

#define STEP(CUR, NXT, KN) LOAD(NXT, KN); MM(CUR);

  LOAD(X, 0);
  STEP(X, Y, 1);
  STEP(Y, X, 2);
  STEP(X, Y, 3);
  STEP(Y, X, 4);
  STEP(X, Y, 5);
  STEP(Y, X, 6);
  STEP(X, Y, 7);
  STEP(Y, X, 8);
  STEP(X, Y, 9);
  STEP(Y, X, 10);
  STEP(X, Y, 11);
  STEP(Y, X, 12);
  STEP(X, Y, 13);
  STEP(Y, X, 14);
  STEP(X, Y, 15);
  STEP(Y, X, 16);
  MM(X);

#undef STEP
#undef MM
#undef LOAD

  // C/D layout: col(out-channel) = lm, row(vertex) = lk*4 + r
  float* op = out + (size_t)b * NV * 64;
  const int gv = vtile + wv * 16 + lk * 4;
  {
    const float bv0 = bias[lm];
    const float bv1 = bias[16 + lm];
    const float bv2 = bias[32 + lm];
    const float bv3 = bias[48 + lm];
    #pragma unroll
    for (int r = 0; r < 4; ++r) {
      float* orow = op + (size_t)(gv + r) * 64;
      orow[lm]      = fmaxf(acc0[r] + bv0, 0.f);
      orow[16 + lm] = fmaxf(acc1[r] + bv1, 0.f);
      orow[32 + lm] = fmaxf(acc2[r] + bv2, 0.f);
      orow[48 + lm] = fmaxf(acc3[r] + bv3, 0.f);
    }
  }
}

extern "C" void kernel_launch(void* const* d_in, const int* in_sizes, int n_in,
                              void* d_out, int out_size, void* d_ws, size_t ws_size,
                              hipStream_t stream) {
  const int* nbr = (const int*)d_in[0];
  // d_in[1] = vertices (unused by the reference computation)
  const float* fm = (const float*)d_in[2];
  const float* w = (const float*)d_in[3];
  const float* bias = (const float*)d_in[4];
  float* out = (float*)d_out;

  unsigned short* fmb = (unsigned short*)d_ws;          // 8*4096*64 bf16 = 4 MB
  unsigned short* wb = fmb + (size_t)8 * NV * 64;       // 17*64*64 bf16

  prep<<<2320, 256, 0, stream>>>(fm, w, fmb, wb);
  conv_main<<<512, 256, 0, stream>>>(nbr, fmb, wb, bias, out);
}